// Round 3
// baseline (531.184 us; speedup 1.0000x reference)
//
#include <hip/hip_runtime.h>
#include <hip/hip_bf16.h>

typedef __hip_bfloat16 bf16;

#define BB 64
#define NN 2048
#define QQ 1024
#define SS 512
#define N_IN 31

__device__ __forceinline__ float bf2f(bf16 v) { return __bfloat162float(v); }

// Robust runtime dtype detection: shell_dirs rows are unit 3-vectors.
// Score both interpretations over 16 rows; true dtype wins the vote.
__device__ int detect_bf16(const void* dirs) {
    int h16 = 0, h32 = 0;
    const float* pf = (const float*)dirs;
    const bf16* ph = (const bf16*)dirs;
    for (int v = 0; v < 16; v++) {
        float a = pf[v * 3 + 0], b = pf[v * 3 + 1], c = pf[v * 3 + 2];
        float n32 = a * a + b * b + c * c;
        float d = bf2f(ph[v * 3 + 0]), e = bf2f(ph[v * 3 + 1]), f = bf2f(ph[v * 3 + 2]);
        float n16 = d * d + e * e + f * f;
        if (fabsf(n32 - 1.f) < 0.03f) h32++;
        if (fabsf(n16 - 1.f) < 0.03f) h16++;
    }
    return h16 > h32 ? 1 : 0;
}

__device__ const int PIDX[36] = {
    0, 2, 5, 8, 12, 17, 22, 27, 32, 38, 45, 52, 59, 66, 73, 80,
    88, 97, 106, 115, 124, 133, 142, 151, 160,
    170, 181, 192, 203, 214, 225, 236, 247, 258, 269, 280};

struct ConvArgs {
    const void* src[N_IN];
    int cnt[N_IN];
    int off[N_IN];
};

// ---------------- convert all inputs to canonical fp32 in workspace ----------------
__global__ __launch_bounds__(256) void k_convert(ConvArgs a, float* __restrict__ dst_base,
                                                 const void* __restrict__ dirs) {
    __shared__ int isbf_s;
    if (threadIdx.x == 0) isbf_s = detect_bf16(dirs);
    __syncthreads();
    int isbf = isbf_s;
    int i = blockIdx.y;
    int n = a.cnt[i];
    float* dst = dst_base + a.off[i];
    const void* s = a.src[i];
    if (isbf) {
        const bf16* sp = (const bf16*)s;
        for (int j = blockIdx.x * 256 + threadIdx.x; j < n; j += gridDim.x * 256)
            dst[j] = bf2f(sp[j]);
    } else {
        const float* sp = (const float*)s;
        for (int j = blockIdx.x * 256 + threadIdx.x; j < n; j += gridDim.x * 256)
            dst[j] = sp[j];
    }
}

// ---------------- prep: transpose D matrices to [t][q], gather pullback cols, rowsum ----------------
__global__ __launch_bounds__(256) void k_prep(const float* __restrict__ De0,
                                              const float* __restrict__ De1,
                                              const float* __restrict__ De2,
                                              float* __restrict__ Dg0t, float* __restrict__ rs0,
                                              float* __restrict__ Det1, float* __restrict__ Det2) {
    __shared__ float tile[32][33];
    int blk = blockIdx.x, tid = threadIdx.x;
    int r = tid >> 5, c = tid & 31;
    if (blk < 192) {  // D_eval1 [1024,165] -> Det1 [165][1024]
        int tq = blk & 31, tt = blk >> 5;
        int q0 = tq * 32, t0 = tt * 32;
        for (int rr = r; rr < 32; rr += 8) {
            int t = t0 + c;
            tile[rr][c] = (t < 165) ? De1[(q0 + rr) * 165 + t] : 0.f;
        }
        __syncthreads();
        for (int rr = r; rr < 32; rr += 8) {
            int t = t0 + rr;
            if (t < 165) Det1[t * QQ + q0 + c] = tile[c][rr];
        }
    } else if (blk < 288) {  // D_eval2 [1024,84] -> Det2 [84][1024]
        int i = blk - 192;
        int tq = i & 31, tt = i >> 5;
        int q0 = tq * 32, t0 = tt * 32;
        for (int rr = r; rr < 32; rr += 8) {
            int t = t0 + c;
            tile[rr][c] = (t < 84) ? De2[(q0 + rr) * 84 + t] : 0.f;
        }
        __syncthreads();
        for (int rr = r; rr < 32; rr += 8) {
            int t = t0 + rr;
            if (t < 84) Det2[t * QQ + q0 + c] = tile[c][rr];
        }
    } else if (blk < 352) {  // gather D_eval0[:, PIDX] -> Dg0t [36][1024]
        int i = blk - 288;
        int tq = i & 31, tj = i >> 5;
        int q0 = tq * 32, j0 = tj * 32;
        for (int rr = r; rr < 32; rr += 8) {
            int j = j0 + c;
            tile[rr][c] = (j < 36) ? De0[(q0 + rr) * 286 + PIDX[j]] : 0.f;
        }
        __syncthreads();
        for (int rr = r; rr < 32; rr += 8) {
            int j = j0 + rr;
            if (j < 36) Dg0t[j * QQ + q0 + c] = tile[c][rr];
        }
    } else {  // rowsum of D_eval0 over all 286 t
        int q = (blk - 352) * 256 + tid;
        float s = 0.f;
        for (int t = 0; t < 286; t++) s += De0[q * 286 + t];
        rs0[q] = s;
    }
}

// ---------------- shells: f[shell][b][s] = mean_n exp(-d2/SIGMA2) ----------------
__global__ __launch_bounds__(256) void k_shells(const float* __restrict__ x,
                                                const float* __restrict__ dirs,
                                                float* __restrict__ fbuf) {
    __shared__ float4 lx[NN];
    int b = blockIdx.x, shell = blockIdx.y, shalf = blockIdx.z;
    const float* xb = x + (size_t)b * NN * 3;
    for (int n = threadIdx.x; n < NN; n += 256) {
        float X = xb[n * 3 + 0];
        float Y = xb[n * 3 + 1];
        float Z = xb[n * 3 + 2];
        lx[n] = make_float4(X, Y, Z, X * X + Y * Y + Z * Z);
    }
    __syncthreads();
    int s = shalf * 256 + threadIdx.x;
    float r = (shell == 0) ? 0.4f : ((shell == 1) ? 0.8f : 1.2f);
    float cx = r * dirs[(shell * SS + s) * 3 + 0];
    float cy = r * dirs[(shell * SS + s) * 3 + 1];
    float cz = r * dirs[(shell * SS + s) * 3 + 2];
    const float KL = 18.033688011112042f;  // log2(e)/SIGMA2, SIGMA2=0.08
    float c2 = cx * cx + cy * cy + cz * cz;
    float base = -KL * c2;
    float cxs = 2.f * KL * cx, cys = 2.f * KL * cy, czs = 2.f * KL * cz;
    float acc = 0.f;
#pragma unroll 4
    for (int n = 0; n < NN; n++) {
        float4 p = lx[n];
        float arg = fmaf(cxs, p.x, fmaf(cys, p.y, fmaf(czs, p.z, fmaf(-KL, p.w, base))));
        acc += exp2f(arg);
    }
    fbuf[(shell * BB + b) * SS + s] = acc * (1.0f / NN);
}

// ---------------- eval0: SH project + mix(W0) + sparse Wigner eval + bias*rowsum ----------------
__global__ __launch_bounds__(256) void k_eval0(const float* __restrict__ fbuf,
                                               const float* __restrict__ A_sh,
                                               const float* __restrict__ W0, const float* __restrict__ b0,
                                               const float* __restrict__ Dg0t, const float* __restrict__ rs0,
                                               float* __restrict__ yq) {
    __shared__ float lf[3][SS];
    __shared__ float lsh[36][3];
    __shared__ float lm[36][16];
    int qc = blockIdx.x, b = blockIdx.y, tid = threadIdx.x;
    for (int i = tid; i < 3 * SS; i += 256)
        ((float*)lf)[i] = fbuf[(i / SS) * (BB * SS) + b * SS + (i % SS)];
    __syncthreads();
    if (tid < 108) {
        int j = tid / 3, c = tid % 3;
        float a = 0.f;
        for (int s = 0; s < SS; s++) a = fmaf(lf[c][s], A_sh[j * SS + s], a);
        lsh[j][c] = a;
    }
    __syncthreads();
    for (int e = tid; e < 576; e += 256) {
        int j = e >> 4, u = e & 15;
        float m = 0.f;
#pragma unroll
        for (int c = 0; c < 3; c++) m = fmaf(lsh[j][c], W0[c * 16 + u], m);
        lm[j][u] = m;
    }
    __syncthreads();
    int q = qc * 256 + tid;
    float acc[16];
#pragma unroll
    for (int u = 0; u < 16; u++) acc[u] = 0.f;
    for (int j = 0; j < 36; j++) {
        float d = Dg0t[j * QQ + q];
#pragma unroll
        for (int u = 0; u < 16; u++) acc[u] = fmaf(d, lm[j][u], acc[u]);
    }
    float rb = rs0[q];
#pragma unroll
    for (int u = 0; u < 16; u++) acc[u] = fmaf(b0[u], rb, acc[u]);
#pragma unroll
    for (int u = 0; u < 16; u++) yq[((size_t)b * 16 + u) * QQ + q] = acc[u];
}

// ---------------- generic eval: mix(W,b) fused + Wigner eval ----------------
template <int TT, int CC, int UU>
__global__ __launch_bounds__(256) void k_eval(const float* __restrict__ yt,
                                              const float* __restrict__ W, const float* __restrict__ bias,
                                              const float* __restrict__ Det,
                                              float* __restrict__ yq) {
    __shared__ float lyt[TT * CC];
    __shared__ float lym[TT * UU];
    int qc = blockIdx.x, b = blockIdx.y, tid = threadIdx.x;
    for (int i = tid; i < TT * CC; i += 256) lyt[i] = yt[(size_t)b * TT * CC + i];
    __syncthreads();
    for (int e = tid; e < TT * UU; e += 256) {
        int t = e / UU, u = e % UU;
        float m = bias[u];
#pragma unroll
        for (int c = 0; c < CC; c++) m = fmaf(lyt[t * CC + c], W[c * UU + u], m);
        lym[e] = m;
    }
    __syncthreads();
    int q = qc * 256 + tid;
    float acc[UU];
#pragma unroll
    for (int u = 0; u < UU; u++) acc[u] = 0.f;
    for (int t = 0; t < TT; t++) {
        float d = Det[t * QQ + q];
#pragma unroll
        for (int u = 0; u < UU; u++) acc[u] = fmaf(d, lym[t * UU + u], acc[u]);
    }
#pragma unroll
    for (int u = 0; u < UU; u++) yq[((size_t)b * UU + u) * QQ + q] = acc[u];
}

// ---------------- stats: deterministic per-channel sum / sumsq over (b, q) ----------------
template <int UU>
__global__ __launch_bounds__(1024) void k_stats(const float* __restrict__ yq, float* __restrict__ stats) {
    __shared__ float sm1[1024];
    __shared__ float sm2[1024];
    int u = blockIdx.x, t = threadIdx.x;
    float s1 = 0.f, s2 = 0.f;
    for (int b = 0; b < BB; b++) {
        float v = yq[((size_t)b * UU + u) * QQ + t];
        s1 += v;
        s2 = fmaf(v, v, s2);
    }
    sm1[t] = s1;
    sm2[t] = s2;
    __syncthreads();
    for (int o = 512; o > 0; o >>= 1) {
        if (t < o) { sm1[t] += sm1[t + o]; sm2[t] += sm2[t + o]; }
        __syncthreads();
    }
    if (t == 0) { stats[u] = sm1[0]; stats[UU + u] = sm2[0]; }
}

// ---------------- generic coef: BN finalize + LeakyReLU fused + Wigner coeff projection ----------------
template <int TT, int UU>
__global__ __launch_bounds__(256) void k_coef(const float* __restrict__ yq,
                                              const float* __restrict__ Dc,
                                              const float* __restrict__ stats,
                                              const float* __restrict__ g, const float* __restrict__ be,
                                              float* __restrict__ out) {
    constexpr int NU = UU / 16;
    __shared__ float lY[UU][132];
    __shared__ float lD[16][132];
    __shared__ float lsu[UU], ltu[UU];
    int tc = blockIdx.x, b = blockIdx.y, tid = threadIdx.x;
    if (tid < UU) {
        const float inv = 1.0f / (BB * QQ);
        float m = stats[tid] * inv;
        float var = stats[UU + tid] * inv - m * m;
        float s = g[tid] * rsqrtf(fmaxf(var, 0.f) + 1e-3f);
        lsu[tid] = s;
        ltu[tid] = be[tid] - m * s;
    }
    __syncthreads();
    int tl = tid >> 4, ul = tid & 15;
    int t = tc * 16 + tl;
    float acc[NU];
#pragma unroll
    for (int i = 0; i < NU; i++) acc[i] = 0.f;
    for (int kc = 0; kc < 8; kc++) {
        for (int i = tid; i < UU * 128; i += 256) {
            int u = i >> 7, qq = i & 127;
            float v = yq[((size_t)b * UU + u) * QQ + kc * 128 + qq];
            v = fmaf(v, lsu[u], ltu[u]);
            lY[u][qq] = (v > 0.f) ? v : 0.3f * v;
        }
        for (int i = tid; i < 16 * 128; i += 256) {
            int t_l = i >> 7, qq = i & 127;
            int tg = tc * 16 + t_l;
            lD[t_l][qq] = (tg < TT) ? Dc[(size_t)tg * QQ + kc * 128 + qq] : 0.f;
        }
        __syncthreads();
        for (int qq = 0; qq < 128; qq++) {
            float d = lD[tl][qq];
#pragma unroll
            for (int iu = 0; iu < NU; iu++) acc[iu] = fmaf(d, lY[ul + 16 * iu][qq], acc[iu]);
        }
        __syncthreads();
    }
    if (t < TT) {
#pragma unroll
        for (int iu = 0; iu < NU; iu++)
            out[((size_t)b * TT + t) * UU + ul + 16 * iu] = acc[iu];
    }
}

// ---------------- degree-wise norms -> ht0 [256 feat][64 batch] ----------------
__global__ __launch_bounds__(256) void k_norms(const float* __restrict__ yt3, float* __restrict__ ht0) {
    int b = blockIdx.x, tid = threadIdx.x;
    int blk = tid >> 6, u = tid & 63;
    const int offs[4] = {0, 1, 10, 35};
    const int ends[4] = {1, 10, 35, 84};
    float a = 0.f;
    for (int t = offs[blk]; t < ends[blk]; t++) {
        float v = yt3[((size_t)b * 84 + t) * 64 + u];
        a = fmaf(v, v, a);
    }
    ht0[(blk * 64 + u) * BB + b] = sqrtf(fmaxf(a, 0.f));
}

// ---------------- fc + batch-BN + relu (lane = batch, wave = feature), LDS reductions ----------------
template <int K, int J>
__global__ __launch_bounds__(512) void k_fc(const float* __restrict__ in, const float* __restrict__ W,
                                            const float* __restrict__ bias, const float* __restrict__ g,
                                            const float* __restrict__ be, float* __restrict__ out) {
    __shared__ float sm1[512];
    __shared__ float sm2[512];
    int tid = threadIdx.x;
    int b = tid & 63;
    int w = tid >> 6;
    int j = blockIdx.x * 8 + w;
    float acc = bias[j];
#pragma unroll 8
    for (int k = 0; k < K; k++) acc = fmaf(in[k * BB + b], W[k * J + j], acc);
    sm1[tid] = acc;
    sm2[tid] = acc * acc;
    __syncthreads();
    for (int o = 32; o > 0; o >>= 1) {
        if (b < o) { sm1[tid] += sm1[tid + o]; sm2[tid] += sm2[tid + o]; }
        __syncthreads();
    }
    float m = sm1[w * 64] * (1.0f / 64.f);
    float var = sm2[w * 64] * (1.0f / 64.f) - m * m;
    float sc = g[j] * rsqrtf(fmaxf(var, 0.f) + 1e-3f);
    float v = (acc - m) * sc + be[j];
    out[j * BB + b] = fmaxf(v, 0.f);
}

// ---------------- output layer + softmax (LDS reductions), dtype-adaptive store ----------------
__global__ __launch_bounds__(64) void k_out(const float* __restrict__ ht2, const float* __restrict__ Wout,
                                            const float* __restrict__ bout, void* __restrict__ outp,
                                            const void* __restrict__ dirs) {
    __shared__ float sm[64];
    __shared__ int isbf_s;
    int b = blockIdx.x, o = threadIdx.x;
    if (o == 0) isbf_s = detect_bf16(dirs);
    float acc = 0.f;
    if (o < 40) {
        acc = bout[o];
        for (int k = 0; k < 256; k++) acc = fmaf(ht2[k * BB + b], Wout[k * 40 + o], acc);
    }
    sm[o] = (o < 40) ? acc : -3.0e38f;
    __syncthreads();
    for (int s = 32; s > 0; s >>= 1) {
        if (o < s) sm[o] = fmaxf(sm[o], sm[o + s]);
        __syncthreads();
    }
    float m = sm[0];
    __syncthreads();
    const float L2E = 1.4426950408889634f;
    float e = (o < 40) ? exp2f((acc - m) * L2E) : 0.f;
    sm[o] = e;
    __syncthreads();
    for (int s = 32; s > 0; s >>= 1) {
        if (o < s) sm[o] += sm[o + s];
        __syncthreads();
    }
    if (o < 40) {
        float p = e / sm[0];
        if (isbf_s) ((bf16*)outp)[b * 40 + o] = __float2bfloat16(p);
        else ((float*)outp)[b * 40 + o] = p;
    }
}

// ---------------- workspace layout (floats) ----------------
#define OFF_FBUF 0
#define OFF_DG0T 98304
#define OFF_RS0 135168
#define OFF_DET1 136192
#define OFF_DET2 305152
#define OFF_YQ 391168
#define OFF_YT1 4585472
#define OFF_YT2 4754432
#define OFF_YT3 4926464
#define OFF_HT0 5270528
#define OFF_HT1 5286912
#define OFF_HT2 5319680
#define OFF_STATS 5336064
#define OFF_CONV 5336320

// element counts + conv-region offsets per input (dict order)
static const int IN_CNT[N_IN] = {
    393216, 4608, 18432, 292864, 168960, 86016, 168960, 86016, 86016,
    48, 16, 512, 32, 2048, 64, 16, 16, 32, 32, 64, 64,
    131072, 512, 512, 512, 131072, 256, 256, 256, 10240, 40};
static const int IN_OFF[N_IN] = {
    0, 393216, 397824, 416256, 709120, 878080, 964096, 1133056, 1219072,
    1305088, 1305136, 1305152, 1305664, 1305696, 1307744, 1307808, 1307824,
    1307840, 1307872, 1307904, 1307968, 1308032, 1439104, 1439616, 1440128,
    1440640, 1571712, 1571968, 1572224, 1572480, 1582720};

extern "C" void kernel_launch(void* const* d_in, const int* in_sizes, int n_in,
                              void* d_out, int out_size, void* d_ws, size_t ws_size,
                              hipStream_t stream) {
    float* ws = (float*)d_ws;
    float* conv = ws + OFF_CONV;

    ConvArgs ca;
    for (int i = 0; i < N_IN; i++) {
        ca.src[i] = d_in[i];
        ca.cnt[i] = IN_CNT[i];
        ca.off[i] = IN_OFF[i];
    }

    const float* x = conv + IN_OFF[0];
    const float* shell_dirs = conv + IN_OFF[1];
    const float* A_sh = conv + IN_OFF[2];
    const float* D_eval0 = conv + IN_OFF[3];
    const float* D_eval1 = conv + IN_OFF[4];
    const float* D_eval2 = conv + IN_OFF[5];
    const float* D_coef1 = conv + IN_OFF[6];
    const float* D_coef2 = conv + IN_OFF[7];
    const float* D_coef_last = conv + IN_OFF[8];
    const float* W0 = conv + IN_OFF[9];
    const float* b0 = conv + IN_OFF[10];
    const float* W1 = conv + IN_OFF[11];
    const float* b1 = conv + IN_OFF[12];
    const float* W2 = conv + IN_OFF[13];
    const float* b2 = conv + IN_OFF[14];
    const float* g0 = conv + IN_OFF[15];
    const float* be0 = conv + IN_OFF[16];
    const float* g1 = conv + IN_OFF[17];
    const float* be1 = conv + IN_OFF[18];
    const float* g2 = conv + IN_OFF[19];
    const float* be2 = conv + IN_OFF[20];
    const float* Wfc1 = conv + IN_OFF[21];
    const float* bfc1 = conv + IN_OFF[22];
    const float* gfc1 = conv + IN_OFF[23];
    const float* befc1 = conv + IN_OFF[24];
    const float* Wfc2 = conv + IN_OFF[25];
    const float* bfc2 = conv + IN_OFF[26];
    const float* gfc2 = conv + IN_OFF[27];
    const float* befc2 = conv + IN_OFF[28];
    const float* Wout = conv + IN_OFF[29];
    const float* bout = conv + IN_OFF[30];

    float* fbuf = ws + OFF_FBUF;
    float* Dg0t = ws + OFF_DG0T;
    float* rs0 = ws + OFF_RS0;
    float* Det1 = ws + OFF_DET1;
    float* Det2 = ws + OFF_DET2;
    float* yq = ws + OFF_YQ;
    float* yt1 = ws + OFF_YT1;
    float* yt2 = ws + OFF_YT2;
    float* yt3 = ws + OFF_YT3;
    float* ht0 = ws + OFF_HT0;
    float* ht1 = ws + OFF_HT1;
    float* ht2 = ws + OFF_HT2;
    float* stats = ws + OFF_STATS;
    float* stats0 = stats;       // 32
    float* stats1 = stats + 32;  // 64
    float* stats2 = stats + 96;  // 128

    k_convert<<<dim3(128, N_IN), 256, 0, stream>>>(ca, conv, d_in[1]);
    k_prep<<<356, 256, 0, stream>>>(D_eval0, D_eval1, D_eval2, Dg0t, rs0, Det1, Det2);
    k_shells<<<dim3(BB, 3, 2), 256, 0, stream>>>(x, shell_dirs, fbuf);
    k_eval0<<<dim3(4, BB), 256, 0, stream>>>(fbuf, A_sh, W0, b0, Dg0t, rs0, yq);
    k_stats<16><<<16, 1024, 0, stream>>>(yq, stats0);
    k_coef<165, 16><<<dim3(11, BB), 256, 0, stream>>>(yq, D_coef1, stats0, g0, be0, yt1);
    k_eval<165, 16, 32><<<dim3(4, BB), 256, 0, stream>>>(yt1, W1, b1, Det1, yq);
    k_stats<32><<<32, 1024, 0, stream>>>(yq, stats1);
    k_coef<84, 32><<<dim3(6, BB), 256, 0, stream>>>(yq, D_coef2, stats1, g1, be1, yt2);
    k_eval<84, 32, 64><<<dim3(4, BB), 256, 0, stream>>>(yt2, W2, b2, Det2, yq);
    k_stats<64><<<64, 1024, 0, stream>>>(yq, stats2);
    k_coef<84, 64><<<dim3(6, BB), 256, 0, stream>>>(yq, D_coef_last, stats2, g2, be2, yt3);
    k_norms<<<BB, 256, 0, stream>>>(yt3, ht0);
    k_fc<256, 512><<<64, 512, 0, stream>>>(ht0, Wfc1, bfc1, gfc1, befc1, ht1);
    k_fc<512, 256><<<32, 512, 0, stream>>>(ht1, Wfc2, bfc2, gfc2, befc2, ht2);
    k_out<<<BB, 64, 0, stream>>>(ht2, Wout, bout, d_out, d_in[1]);
}